// Round 15
// baseline (299.450 us; speedup 1.0000x reference)
//
#include <hip/hip_runtime.h>
#include <cstddef>
#include <cstdint>

#define N_SH 1195
#define N_SS 390
#define N_HH 805
#define DIM  64

typedef __bf16 bf16_t;
typedef bf16_t bf16x4v __attribute__((ext_vector_type(4)));
typedef bf16_t bf16x8v __attribute__((ext_vector_type(8)));
typedef float f32x4 __attribute__((ext_vector_type(4)));

__device__ inline ushort f2bf(float f) {
    union { float f; uint32_t u; } c; c.f = f;
    uint32_t u = c.u;
    u += 0x7FFFu + ((u >> 16) & 1u);
    return (ushort)(u >> 16);
}

// bijective XCD swizzle (m204)
__device__ inline void xcd_swizzle(int gx, int gy, int& bx, int& by) {
    int nwg = gx * gy;
    int lin = by * gx + bx;
    int q = nwg >> 3, r = nwg & 7;
    int xcd = lin & 7, idx = lin >> 3;
    int nt = (xcd < r ? xcd * (q + 1) : r * (q + 1) + (xcd - r) * q) + idx;
    by = nt / gx; bx = nt % gx;
}

// ---------------- adjacency build: packed 4x8-bit counters, all 3 graphs ----
__global__ void build_adj3_kernel(
    const int* __restrict__ e1, int E1, int hs1, uint32_t* __restrict__ T1,
    const int* __restrict__ e2, int E2, int hs2, uint32_t* __restrict__ T2,
    const int* __restrict__ e3, int E3, int hs3, uint32_t* __restrict__ T3)
{
    int i = blockIdx.x * blockDim.x + threadIdx.x;
    if (i < E1) {
        int src = e1[i], dst = e1[E1 + i];
        atomicAdd(&T1[(size_t)dst * hs1 + (src >> 2)], 1u << ((src & 3) * 8));
    } else if (i < E1 + E2) {
        int j = i - E1;
        int src = e2[j], dst = e2[E2 + j];
        atomicAdd(&T2[(size_t)dst * hs2 + (src >> 2)], 1u << ((src & 3) * 8));
    } else if (i < E1 + E2 + E3) {
        int j = i - E1 - E2;
        int src = e3[j], dst = e3[E3 + j];
        atomicAdd(&T3[(size_t)dst * hs3 + (src >> 2)], 1u << ((src & 3) * 8));
    }
}

__device__ inline void unpack_one(const uint32_t* __restrict__ T, int R, int C,
                                  int hs, ushort* __restrict__ out, int Cp, int i) {
    int r = i / Cp, c = i % Cp;
    float v = 0.f;
    if (r < R && c < C) {
        uint32_t w = T[(size_t)r * hs + (c >> 2)];
        v = (float)((w >> ((c & 3) * 8)) & 0xFFu);
    }
    out[i] = f2bf(v);
}

// mega-prep: unpack adj + rowsum + cat weights + concat_hh + zero scratch
__global__ void mega_prep_kernel(
    const uint32_t* __restrict__ T1, int hs1, ushort* __restrict__ o1, int n1, int Cp1,
    const uint32_t* __restrict__ T2, int hs2, ushort* __restrict__ o2, int n2, int Cp2,
    const uint32_t* __restrict__ T3, int hs3, ushort* __restrict__ o3, int n3, int Cp3,
    float* __restrict__ cntInv,
    const float* __restrict__ w_sh1, const float* __restrict__ w_sh1h,
    const float* __restrict__ b_sh1, const float* __restrict__ b_sh1h,
    const float* __restrict__ w_sh2, const float* __restrict__ w_sh2h,
    const float* __restrict__ b_sh2, const float* __restrict__ b_sh2h,
    const float* __restrict__ w_mlp1, const float* __restrict__ w_mlp1h,
    const float* __restrict__ b_mlp1, const float* __restrict__ b_mlp1h,
    float* __restrict__ W1cat, float* __restrict__ b1cat,
    float* __restrict__ W2bd,  float* __restrict__ b2cat,
    float* __restrict__ WMbd,  float* __restrict__ bMcat,
    const float* __restrict__ emb, const float* __restrict__ kg,
    float* __restrict__ xhh0,
    float* __restrict__ zeroF, int nZeroF,
    ushort* __restrict__ zeroH, int nZeroH)
{
    int i = blockIdx.x * blockDim.x + threadIdx.x;
    if (i < n1) { unpack_one(T1, N_SH, N_SH, hs1, o1, Cp1, i); return; }
    i -= n1;
    if (i < n2) { unpack_one(T2, N_SS, N_SS, hs2, o2, Cp2, i); return; }
    i -= n2;
    if (i < n3) { unpack_one(T3, N_HH, N_HH, hs3, o3, Cp3, i); return; }
    i -= n3;
    if (i < N_SH * 64) {
        int row = i >> 6, lane = i & 63;
        const uint32_t* p = T1 + (size_t)row * hs1;
        uint32_t s = 0;
        for (int c = lane; c < hs1; c += 64) {
            uint32_t w0 = p[c];
            s += (w0 & 0xFFu) + ((w0 >> 8) & 0xFFu) + ((w0 >> 16) & 0xFFu) + (w0 >> 24);
        }
        for (int off = 32; off > 0; off >>= 1) s += __shfl_down(s, off);
        if (lane == 0) cntInv[row] = 1.0f / fmaxf((float)s, 1.0f);
        return;
    }
    i -= N_SH * 64;
    if (i < 64 * 128) {
        int k = i >> 7, j = i & 127;
        W1cat[i] = (j < 64) ? w_sh1[k * 64 + j] : w_sh1h[k * 64 + (j - 64)];
        return;
    }
    i -= 64 * 128;
    if (i < 128) { b1cat[i] = (i < 64) ? b_sh1[i] : b_sh1h[i - 64]; return; }
    i -= 128;
    if (i < 128 * 128) {
        int k = i >> 7, j = i & 127;
        float v = 0.f;
        if (k < 64 && j < 64) v = w_sh2[k * 64 + j];
        else if (k >= 64 && j >= 64) v = w_sh2h[(k - 64) * 64 + (j - 64)];
        W2bd[i] = v;
        return;
    }
    i -= 128 * 128;
    if (i < 128) { b2cat[i] = (i < 64) ? b_sh2[i] : b_sh2h[i - 64]; return; }
    i -= 128;
    if (i < 128 * 512) {
        int k = i >> 9, j = i & 511;
        float v = 0.f;
        if (j < 256) { if (k < 64) v = w_mlp1[k * 256 + j]; }
        else         { if (k >= 64) v = w_mlp1h[(k - 64) * 256 + (j - 256)]; }
        WMbd[i] = v;
        return;
    }
    i -= 128 * 512;
    if (i < 512) { bMcat[i] = (i < 256) ? b_mlp1[i] : b_mlp1h[i - 256]; return; }
    i -= 512;
    if (i < N_HH * 91) {
        int r = i / 91, c = i % 91;
        xhh0[i] = (c < DIM) ? emb[r * DIM + c] : kg[r * 27 + (c - DIM)];
        return;
    }
    i -= N_HH * 91;
    if (i < nZeroF) { zeroF[i] = 0.f; return; }
    i -= nZeroF;
    if (i < nZeroH) { zeroH[i] = 0; }
}

// -------- fp32 GEMM body (device fn): A2 add, BN-on-A, transposed-bf16 out --
#define BM 64
#define BN 64
#define BK 16

__device__ __forceinline__ void gemm_body(
    const float* __restrict__ A, const float* __restrict__ A2, int ldaA, int ldaA2,
    const float* __restrict__ B, const float* __restrict__ bias,
    float* __restrict__ C, ushort* __restrict__ outT, int ldt,
    int M, int N, int K, float* __restrict__ statsOut, int statsStride,
    const float* __restrict__ bnStats, const float* __restrict__ bnG,
    const float* __restrict__ bnBe, int bnM,
    int bx, int by, int tid,
    float* __restrict__ AsBuf, float* __restrict__ BsBuf,
    float* __restrict__ cs, float* __restrict__ sA, float* __restrict__ tA)
{
    const int row0 = by * BM;
    const int col0 = bx * BN;
    const int tr  = (tid >> 4) << 2;
    const int tc  = (tid & 15) << 2;
    const int lar = tid >> 2;
    const int lac = (tid & 3) << 2;
    const int lbr = tid >> 4;
    const int lbc = (tid & 15) << 2;

    if (bnStats) {
        float invM = 1.0f / (float)bnM;
        float mean = bnStats[tid] * invM;
        float var  = fmaxf(bnStats[512 + tid] * invM - mean * mean, 0.f);
        float scv  = bnG[tid] * rsqrtf(var + 1e-5f);
        sA[tid] = scv;
        tA[tid] = bnBe[tid] - mean * scv;
        __syncthreads();
    }

    float acc[4][4] = {{0.f}};

    for (int k0 = 0; k0 < K; k0 += BK) {
        const int gr = row0 + lar;
        #pragma unroll
        for (int i = 0; i < 4; ++i) {
            int gk = k0 + lac + i;
            float v = 0.f;
            if (gr < M && gk < K) {
                v = A[(size_t)gr * ldaA + gk];
                if (bnStats) v = tanhf(v * sA[gk] + tA[gk]);
                if (A2) v += A2[(size_t)gr * ldaA2 + gk];
            }
            AsBuf[(lac + i) * (BM + 4) + lar] = v;
        }
        const int gk = k0 + lbr;
        const float* Bp = B + (size_t)gk * N + col0 + lbc;
        #pragma unroll
        for (int i = 0; i < 4; ++i) {
            int gc = col0 + lbc + i;
            BsBuf[lbr * BN + lbc + i] = (gk < K && gc < N) ? Bp[i] : 0.f;
        }
        __syncthreads();
        #pragma unroll
        for (int kk = 0; kk < BK; ++kk) {
            float4 a = *reinterpret_cast<const float4*>(&AsBuf[kk * (BM + 4) + tr]);
            float4 b = *reinterpret_cast<const float4*>(&BsBuf[kk * BN + tc]);
            acc[0][0] += a.x * b.x; acc[0][1] += a.x * b.y; acc[0][2] += a.x * b.z; acc[0][3] += a.x * b.w;
            acc[1][0] += a.y * b.x; acc[1][1] += a.y * b.y; acc[1][2] += a.y * b.z; acc[1][3] += a.y * b.w;
            acc[2][0] += a.z * b.x; acc[2][1] += a.z * b.y; acc[2][2] += a.z * b.z; acc[2][3] += a.z * b.w;
            acc[3][0] += a.w * b.x; acc[3][1] += a.w * b.y; acc[3][2] += a.w * b.z; acc[3][3] += a.w * b.w;
        }
        __syncthreads();
    }

    float ls[4] = {0.f, 0.f, 0.f, 0.f}, lq[4] = {0.f, 0.f, 0.f, 0.f};
    #pragma unroll
    for (int i = 0; i < 4; ++i) {
        int gr = row0 + tr + i;
        if (gr >= M) continue;
        #pragma unroll
        for (int j = 0; j < 4; ++j) {
            int gc = col0 + tc + j;
            if (gc >= N) continue;
            float v = acc[i][j];
            if (bias) v += bias[gc];
            if (outT) outT[(size_t)gc * ldt + gr] = f2bf(v);
            else      C[(size_t)gr * N + gc] = v;
            ls[j] += v; lq[j] += v * v;
        }
    }

    if (statsOut) {
        if (tid < 128) cs[tid] = 0.f;
        __syncthreads();
        #pragma unroll
        for (int j = 0; j < 4; ++j) {
            atomicAdd(&cs[tc + j], ls[j]);
            atomicAdd(&cs[64 + tc + j], lq[j]);
        }
        __syncthreads();
        if (tid < 64) {
            atomicAdd(&statsOut[col0 + tid], cs[tid]);
            atomicAdd(&statsOut[statsStride + col0 + tid], cs[64 + tid]);
        }
    }
}

__global__ __launch_bounds__(256) void gemm_kernel(
    const float* __restrict__ A, const float* __restrict__ A2, int ldaA, int ldaA2,
    const float* __restrict__ B, const float* __restrict__ bias,
    float* __restrict__ C, ushort* __restrict__ outT, int ldt,
    int M, int N, int K, float* __restrict__ statsOut, int statsStride,
    const float* __restrict__ bnStats, const float* __restrict__ bnG,
    const float* __restrict__ bnBe, int bnM)
{
    __shared__ float As[BK * (BM + 4)];
    __shared__ float Bs[BK * BN];
    __shared__ float cs[128];
    __shared__ float sA[256], tA[256];
    gemm_body(A, A2, ldaA, ldaA2, B, bias, C, outT, ldt, M, N, K,
              statsOut, statsStride, bnStats, bnG, bnBe, bnM,
              blockIdx.x, blockIdx.y, threadIdx.x, As, Bs, cs, sA, tA);
}

// SS (z=0) + HH (z=1) linear layers in one launch
__global__ __launch_bounds__(256) void gemm_side_kernel(
    const float* __restrict__ emb, const float* __restrict__ w_ss,
    const float* __restrict__ b_ss, ushort* __restrict__ HSST,
    const float* __restrict__ xhh0, const float* __restrict__ w_hh,
    const float* __restrict__ b_hh, ushort* __restrict__ HHHT,
    int KP1v, int KHHv)
{
    __shared__ float As[BK * (BM + 4)];
    __shared__ float Bs[BK * BN];
    __shared__ float cs[128];
    __shared__ float sA[256], tA[256];
    if (blockIdx.z == 0) {
        if (blockIdx.y >= 7) return;
        gemm_body(emb, nullptr, 64, 0, w_ss, b_ss, nullptr, HSST, KP1v,
                  N_SS, 256, 64, nullptr, 0, nullptr, nullptr, nullptr, 0,
                  blockIdx.x, blockIdx.y, threadIdx.x, As, Bs, cs, sA, tA);
    } else {
        gemm_body(xhh0, nullptr, 91, 0, w_hh, b_hh, nullptr, HHHT, KHHv,
                  N_HH, 256, 91, nullptr, 0, nullptr, nullptr, nullptr, 0,
                  blockIdx.x, blockIdx.y, threadIdx.x, As, Bs, cs, sA, tA);
    }
}

// ---------------- split-K MFMA body ------------------------------------------
#define LDT 40
#define OLW 132

__device__ __forceinline__ void splitk_body(
    const ushort* __restrict__ A, const ushort* __restrict__ Bt,
    int M, int K, int lda, int kChunk, int Ntot,
    float* __restrict__ part, int bx, int by, int bz, int tid,
    ushort* __restrict__ As, ushort* __restrict__ Bs)
{
    const int row0 = by * 128;
    const int col0 = bx * 128;
    const int wid  = tid >> 6, lane = tid & 63;
    const int wr = wid >> 1, wc = wid & 1;
    const int l15 = lane & 15, lg = lane >> 4;
    const int kg = lg * 4;
    const int sr = tid >> 2;
    const int sc = (tid & 3) * 8;

    const int k0s = bz * kChunk;
    const int k0e = (k0s + kChunk < K) ? k0s + kChunk : K;

    const ushort* pA0 = A  + (size_t)(row0 + sr)      * lda + sc;
    const ushort* pA1 = A  + (size_t)(row0 + sr + 64) * lda + sc;
    const ushort* pB0 = Bt + (size_t)(col0 + sr)      * lda + sc;
    const ushort* pB1 = Bt + (size_t)(col0 + sr + 64) * lda + sc;

    uint4 ra0 = *reinterpret_cast<const uint4*>(pA0 + k0s);
    uint4 ra1 = *reinterpret_cast<const uint4*>(pA1 + k0s);
    uint4 rb0 = *reinterpret_cast<const uint4*>(pB0 + k0s);
    uint4 rb1 = *reinterpret_cast<const uint4*>(pB1 + k0s);

    f32x4 acc[4][4];
    #pragma unroll
    for (int m = 0; m < 4; ++m)
        #pragma unroll
        for (int n = 0; n < 4; ++n) acc[m][n] = (f32x4)0.f;

    for (int k0 = k0s; k0 < k0e; k0 += 32) {
        *reinterpret_cast<uint4*>(&As[sr * LDT + sc])        = ra0;
        *reinterpret_cast<uint4*>(&As[(sr + 64) * LDT + sc]) = ra1;
        *reinterpret_cast<uint4*>(&Bs[sr * LDT + sc])        = rb0;
        *reinterpret_cast<uint4*>(&Bs[(sr + 64) * LDT + sc]) = rb1;
        __syncthreads();
        if (k0 + 32 < k0e) {
            ra0 = *reinterpret_cast<const uint4*>(pA0 + k0 + 32);
            ra1 = *reinterpret_cast<const uint4*>(pA1 + k0 + 32);
            rb0 = *reinterpret_cast<const uint4*>(pB0 + k0 + 32);
            rb1 = *reinterpret_cast<const uint4*>(pB1 + k0 + 32);
        }

        bf16x8v af[4], bfr[4];
        #pragma unroll
        for (int m = 0; m < 4; ++m) {
            int ar = wr * 64 + m * 16 + l15;
            bf16x4v lo = *reinterpret_cast<const bf16x4v*>(&As[ar * LDT + kg]);
            bf16x4v hi = *reinterpret_cast<const bf16x4v*>(&As[ar * LDT + kg + 16]);
            af[m] = __builtin_shufflevector(lo, hi, 0, 1, 2, 3, 4, 5, 6, 7);
        }
        #pragma unroll
        for (int n = 0; n < 4; ++n) {
            int br = wc * 64 + n * 16 + l15;
            bf16x4v lo = *reinterpret_cast<const bf16x4v*>(&Bs[br * LDT + kg]);
            bf16x4v hi = *reinterpret_cast<const bf16x4v*>(&Bs[br * LDT + kg + 16]);
            bfr[n] = __builtin_shufflevector(lo, hi, 0, 1, 2, 3, 4, 5, 6, 7);
        }
        #pragma unroll
        for (int m = 0; m < 4; ++m)
            #pragma unroll
            for (int n = 0; n < 4; ++n)
                acc[m][n] = __builtin_amdgcn_mfma_f32_16x16x32_bf16(af[m], bfr[n], acc[m][n], 0, 0, 0);
        __syncthreads();
    }

    float* pslab = part + (size_t)bz * M * Ntot;
    #pragma unroll
    for (int m = 0; m < 4; ++m) {
        int grow_base = row0 + wr * 64 + m * 16 + kg;
        #pragma unroll
        for (int j = 0; j < 4; ++j) {
            int grow = grow_base + j;
            if (grow >= M) continue;
            #pragma unroll
            for (int n = 0; n < 4; ++n) {
                int gcol = col0 + wc * 64 + n * 16 + l15;
                pslab[(size_t)grow * Ntot + gcol] = acc[m][n][j];
            }
        }
    }
}

__global__ __launch_bounds__(256) void mfma_splitk_kernel(
    const ushort* __restrict__ A, const ushort* __restrict__ Bt,
    int M, int K, int lda, int kChunk, int Ntot, float* __restrict__ part)
{
    __shared__ __align__(16) ushort As[128 * LDT];
    __shared__ __align__(16) ushort Bs[128 * LDT];
    splitk_body(A, Bt, M, K, lda, kChunk, Ntot, part,
                blockIdx.x, blockIdx.y, blockIdx.z, threadIdx.x, As, Bs);
}

// SS (z<4) + HH (z>=4) splitk in one launch
__global__ __launch_bounds__(256) void mfma_splitk_side_kernel(
    const ushort* __restrict__ adjSS, const ushort* __restrict__ HSST, int KP1v,
    float* __restrict__ pSS,
    const ushort* __restrict__ adjHH, const ushort* __restrict__ HHHT, int KHHv,
    float* __restrict__ pHH)
{
    __shared__ __align__(16) ushort As[128 * LDT];
    __shared__ __align__(16) ushort Bs[128 * LDT];
    if (blockIdx.z < 4) {
        if (blockIdx.y >= 4) return;
        splitk_body(adjSS, HSST, N_SS, KP1v, KP1v, 128, 256, pSS,
                    blockIdx.x, blockIdx.y, blockIdx.z, threadIdx.x, As, Bs);
    } else {
        splitk_body(adjHH, HHHT, N_HH, KHHv, KHHv, 128, 256, pHH,
                    blockIdx.x, blockIdx.y, blockIdx.z - 4, threadIdx.x, As, Bs);
    }
}

// reduce partials; t = tanh(sum*rs). emb? out = (emb + prev + t)/3 : out = t
__global__ void reduce_tanh_kernel(const float* __restrict__ part, int S, int M, int N,
                                   const float* __restrict__ rs,
                                   const float* __restrict__ emb,
                                   const float* __restrict__ prev,
                                   float* __restrict__ out) {
    int i = blockIdx.x * blockDim.x + threadIdx.x;
    if (i >= M * N) return;
    int r = i / N, j = i - r * N;
    float s = 0.f;
    for (int z = 0; z < S; ++z) s += part[(size_t)z * M * N + i];
    if (rs) s *= rs[r];
    float t = tanhf(s);
    if (emb) out[i] = (emb[r * 64 + (j & 63)] + prev[i] + t) * (1.0f / 3.0f);
    else     out[i] = t;
}

// merged SS+HH reduce
__global__ void reduce_side_kernel(const float* __restrict__ pSS, float* __restrict__ ss1,
                                   const float* __restrict__ pHH, float* __restrict__ hh1) {
    int i = blockIdx.x * blockDim.x + threadIdx.x;
    const int nSS = N_SS * 256;
    const int nHH = N_HH * 256;
    if (i < nSS) {
        float s = 0.f;
        for (int z = 0; z < 4; ++z) s += pSS[(size_t)z * nSS + i];
        ss1[i] = tanhf(s);
        return;
    }
    i -= nSS;
    if (i < nHH) {
        float s = 0.f;
        for (int z = 0; z < 7; ++z) s += pHH[(size_t)z * nHH + i];
        hh1[i] = tanhf(s);
    }
}

// ---------------- C1': bufM = (P @ D^T)·(1/rowsum(P)) + b_mlp, BN stats -----
__device__ inline void loadP8(const float* __restrict__ rowp, int c0, bool rv,
                              float* a, float& s) {
    if (rv && c0 + 8 <= N_SS) {
        float2 x0 = *reinterpret_cast<const float2*>(rowp + c0);
        float2 x1 = *reinterpret_cast<const float2*>(rowp + c0 + 2);
        float2 x2 = *reinterpret_cast<const float2*>(rowp + c0 + 4);
        float2 x3 = *reinterpret_cast<const float2*>(rowp + c0 + 6);
        a[0] = x0.x; a[1] = x0.y; a[2] = x1.x; a[3] = x1.y;
        a[4] = x2.x; a[5] = x2.y; a[6] = x3.x; a[7] = x3.y;
    } else {
        #pragma unroll
        for (int i = 0; i < 8; ++i) a[i] = (rv && (c0 + i) < N_SS) ? rowp[c0 + i] : 0.f;
    }
    #pragma unroll
    for (int i = 0; i < 8; ++i) s += a[i];
}

__global__ __launch_bounds__(256) void mfma_c1_kernel(
    const float* __restrict__ Pm, const ushort* __restrict__ Dt,
    int M, const float* __restrict__ bias,
    float* __restrict__ outF, float* __restrict__ statsOut)
{
    __shared__ __align__(16) uint8_t smemRaw[128 * LDT * 2 * 2];
    ushort* As = (ushort*)smemRaw;
    ushort* Bs = (ushort*)(smemRaw + 128 * LDT * 2);
    float*  oLds = (float*)smemRaw;
    __shared__ float sums[128];
    __shared__ float cs[256];
    const int tid  = threadIdx.x;
    int bx = blockIdx.x, by = blockIdx.y;
    xcd_swizzle(gridDim.x, gridDim.y, bx, by);
    const int row0 = by * 128;
    const int col0 = bx * 128;
    const int wid  = tid >> 6, lane = tid & 63;
    const int wr = wid >> 1, wc = wid & 1;
    const int l15 = lane & 15, lg = lane >> 4;
    const int kg = lg * 4;
    const int sr = tid >> 2;
    const int sc = (tid & 3) * 8;

    const float* pA0 = Pm + (size_t)(row0 + sr)      * N_SS;
    const float* pA1 = Pm + (size_t)(row0 + sr + 64) * N_SS;
    const bool rv0 = (row0 + sr)      < M;
    const bool rv1 = (row0 + sr + 64) < M;
    const ushort* pB0 = Dt + (size_t)(col0 + sr)      * 416 + sc;
    const ushort* pB1 = Dt + (size_t)(col0 + sr + 64) * 416 + sc;

    float a0[8], a1[8];
    float s0 = 0.f, s1 = 0.f;
    loadP8(pA0, sc, rv0, a0, s0);
    loadP8(pA1, sc, rv1, a1, s1);
    uint4 b0 = *reinterpret_cast<const uint4*>(pB0);
    uint4 b1 = *reinterpret_cast<const uint4*>(pB1);

    f32x4 acc[4][4];
    #pragma unroll
    for (int m = 0; m < 4; ++m)
        #pragma unroll
        for (int n = 0; n < 4; ++n) acc[m][n] = (f32x4)0.f;

    for (int k0 = 0; k0 < 416; k0 += 32) {
        {
            bf16_t h[8];
            #pragma unroll
            for (int i = 0; i < 8; ++i) h[i] = (bf16_t)a0[i];
            *reinterpret_cast<uint4*>(&As[sr * LDT + sc]) = *reinterpret_cast<const uint4*>(h);
            #pragma unroll
            for (int i = 0; i < 8; ++i) h[i] = (bf16_t)a1[i];
            *reinterpret_cast<uint4*>(&As[(sr + 64) * LDT + sc]) = *reinterpret_cast<const uint4*>(h);
        }
        *reinterpret_cast<uint4*>(&Bs[sr * LDT + sc])        = b0;
        *reinterpret_cast<uint4*>(&Bs[(sr + 64) * LDT + sc]) = b1;
        __syncthreads();
        if (k0 + 32 < 416) {
            loadP8(pA0, k0 + 32 + sc, rv0, a0, s0);
            loadP8(pA1, k0 + 32 + sc, rv1, a1, s1);
            b0 = *reinterpret_cast<const uint4*>(pB0 + k0 + 32);
            b1 = *reinterpret_cast<const uint4*>(pB1 + k0 + 32);
        }

        bf16x8v af[4], bfr[4];
        #pragma unroll
        for (int m = 0; m < 4; ++m) {
            int ar = wr * 64 + m * 16 + l15;
            bf16x4v lo = *reinterpret_cast<const bf16x4v*>(&As[ar * LDT + kg]);
            bf16x4v hi = *reinterpret_cast<const bf16x4v*>(&As[ar * LDT + kg + 16]);
            af[m] = __builtin_shufflevector(lo, hi, 0, 1, 2, 3, 4, 5, 6, 7);
        }
        #pragma unroll
        for (int n = 0; n < 4; ++n) {
            int br = wc * 64 + n * 16 + l15;
            bf16x4v lo = *reinterpret_cast<const bf16x4v*>(&Bs[br * LDT + kg]);
            bf16x4v hi = *reinterpret_cast<const bf16x4v*>(&Bs[br * LDT + kg + 16]);
            bfr[n] = __builtin_shufflevector(lo, hi, 0, 1, 2, 3, 4, 5, 6, 7);
        }
        #pragma unroll
        for (int m = 0; m < 4; ++m)
            #pragma unroll
            for (int n = 0; n < 4; ++n)
                acc[m][n] = __builtin_amdgcn_mfma_f32_16x16x32_bf16(af[m], bfr[n], acc[m][n], 0, 0, 0);
        __syncthreads();
    }

    if (tid < 128) sums[tid] = 0.f;
    if (tid < 256) cs[tid] = 0.f;
    __syncthreads();
    atomicAdd(&sums[sr], s0);
    atomicAdd(&sums[sr + 64], s1);
    __syncthreads();

    float ls[4] = {0.f, 0.f, 0.f, 0.f}, lq[4] = {0.f, 0.f, 0.f, 0.f};
    #pragma unroll
    for (int m = 0; m < 4; ++m) {
        int lr_base = wr * 64 + m * 16 + kg;
        #pragma unroll
        for (int j = 0; j < 4; ++j) {
            int lr = lr_base + j;
            int grow = row0 + lr;
            float t = sums[lr];
            float inv = (t != 0.f) ? 1.0f / t : 0.f;
            #pragma unroll
            for (int n = 0; n < 4; ++n) {
                int gcol = col0 + wc * 64 + n * 16 + l15;
                float v = acc[m][n][j] * inv + bias[gcol];
                acc[m][n][j] = v;
                if (grow < M) { ls[n] += v; lq[n] += v * v; }
            }
        }
    }

    #pragma unroll
    for (int n = 0; n < 4; ++n) {
        int lc = wc * 64 + n * 16 + l15;
        atomicAdd(&cs[lc], ls[n]);
        atomicAdd(&cs[128 + lc], lq[n]);
    }
    __syncthreads();
    if (tid < 128) {
        atomicAdd(&statsOut[col0 + tid], cs[tid]);
        atomicAdd(&statsOut[256 + col0 + tid], cs[128 + tid]);
    }

    for (int m = 0; m < 4; ++m) {
        __syncthreads();
        #pragma unroll
        for (int n = 0; n < 4; ++n)
            #pragma unroll
            for (int j = 0; j < 4; ++j)
                oLds[(wr * 16 + kg + j) * OLW + wc * 64 + n * 16 + l15] = acc[m][n][j];
        __syncthreads();
        #pragma unroll
        for (int rr = 0; rr < 8; ++rr) {
            int lrow = wid * 8 + rr;
            int band = lrow >> 4;
            int r16  = lrow & 15;
            int grow = row0 + band * 64 + m * 16 + r16;
            if (grow < M) {
                float v0 = oLds[lrow * OLW + lane];
                float v1 = oLds[lrow * OLW + 64 + lane];
                outF[(size_t)grow * 256 + col0 + lane]      = v0;
                outF[(size_t)grow * 256 + col0 + 64 + lane] = v1;
            }
        }
    }
}

// ------ C3: 128x256 tile, A = relu(BN(bufM)), depth-1 prefetch --------------
__global__ __launch_bounds__(256) void mfma_c3_kernel(
    const float* __restrict__ Abuf, const ushort* __restrict__ Bt,
    int M, int Nw,
    const float* __restrict__ stats, const float* __restrict__ g,
    const float* __restrict__ be,
    float* __restrict__ outF, int ldo)
{
    __shared__ __align__(16) ushort As[128 * LDT];   // 10240 B
    __shared__ __align__(16) ushort Bs[256 * LDT];   // 20480 B
    __shared__ float sscale[256], sshift[256];
    const int tid  = threadIdx.x;
    int bx = blockIdx.x, by = blockIdx.y;
    xcd_swizzle(gridDim.x, gridDim.y, bx, by);
    const int row0 = by * 128;
    const int col0 = bx * 256;
    const int wid  = tid >> 6, lane = tid & 63;
    const int wr = wid >> 1, wc = wid & 1;       // wave: rows wr*64.., cols wc*128..
    const int l15 = lane & 15, lg = lane >> 4;
    const int kg = lg * 4;
    const int sr = tid >> 2;
    const int sc = (tid & 3) * 8;

    if (tid < 256) {
        float invM = 1.0f / (float)M;
        float mean = stats[tid] * invM;
        float var  = fmaxf(stats[256 + tid] * invM - mean * mean, 0.f);
        float scv  = g[tid] * rsqrtf(var + 1e-5f);
        sscale[tid] = scv;
        sshift[tid] = be[tid] - mean * scv;
    }
    __syncthreads();

    const float*  pA0 = Abuf + (size_t)(row0 + sr)      * 256 + sc;
    const float*  pA1 = Abuf + (size_t)(row0 + sr + 64) * 256 + sc;
    const ushort* pB0 = Bt + (size_t)(col0 + sr)        * 256 + sc;
    const ushort* pB1 = Bt + (size_t)(col0 + sr + 64)   * 256 + sc;
    const ushort* pB2 = Bt + (size_t)(col0 + sr + 128)  * 256 + sc;
    const ushort* pB3 = Bt + (size_t)(col0 + sr + 192)  * 256 + sc;

    float4 a00 = *reinterpret_cast<const float4*>(pA0);
    float4 a01 = *reinterpret_cast<const float4*>(pA0 + 4);
    float4 a10 = *reinterpret_cast<const float4*>(pA1);
    float4 a11 = *reinterpret_cast<const float4*>(pA1 + 4);
    uint4  b0  = *reinterpret_cast<const uint4*>(pB0);
    uint4  b1  = *reinterpret_cast<const uint4*>(pB1);
    uint4  b2  = *reinterpret_cast<const uint4*>(pB2);
    uint4  b3  = *reinterpret_cast<const uint4*>(pB3);

    f32x4 acc[4][8];
    #pragma unroll
    for (int m = 0; m < 4; ++m)
        #pragma unroll
        for (int n = 0; n < 8; ++n) acc[m][n] = (f32x4)0.f;

    for (int k0 = 0; k0 < 256; k0 += 32) {
        float s8[8], t8[8];
        #pragma unroll
        for (int i = 0; i < 8; ++i) { s8[i] = sscale[k0 + sc + i]; t8[i] = sshift[k0 + sc + i]; }
        {
            bf16_t h[8];
            h[0] = (bf16_t)fmaxf(a00.x * s8[0] + t8[0], 0.f);
            h[1] = (bf16_t)fmaxf(a00.y * s8[1] + t8[1], 0.f);
            h[2] = (bf16_t)fmaxf(a00.z * s8[2] + t8[2], 0.f);
            h[3] = (bf16_t)fmaxf(a00.w * s8[3] + t8[3], 0.f);
            h[4] = (bf16_t)fmaxf(a01.x * s8[4] + t8[4], 0.f);
            h[5] = (bf16_t)fmaxf(a01.y * s8[5] + t8[5], 0.f);
            h[6] = (bf16_t)fmaxf(a01.z * s8[6] + t8[6], 0.f);
            h[7] = (bf16_t)fmaxf(a01.w * s8[7] + t8[7], 0.f);
            *reinterpret_cast<uint4*>(&As[sr * LDT + sc]) = *reinterpret_cast<const uint4*>(h);
            h[0] = (bf16_t)fmaxf(a10.x * s8[0] + t8[0], 0.f);
            h[1] = (bf16_t)fmaxf(a10.y * s8[1] + t8[1], 0.f);
            h[2] = (bf16_t)fmaxf(a10.z * s8[2] + t8[2], 0.f);
            h[3] = (bf16_t)fmaxf(a10.w * s8[3] + t8[3], 0.f);
            h[4] = (bf16_t)fmaxf(a11.x * s8[4] + t8[4], 0.f);
            h[5] = (bf16_t)fmaxf(a11.y * s8[5] + t8[5], 0.f);
            h[6] = (bf16_t)fmaxf(a11.z * s8[6] + t8[6], 0.f);
            h[7] = (bf16_t)fmaxf(a11.w * s8[7] + t8[7], 0.f);
            *reinterpret_cast<uint4*>(&As[(sr + 64) * LDT + sc]) = *reinterpret_cast<const uint4*>(h);
        }
        *reinterpret_cast<uint4*>(&Bs[sr * LDT + sc])         = b0;
        *reinterpret_cast<uint4*>(&Bs[(sr + 64) * LDT + sc])  = b1;
        *reinterpret_cast<uint4*>(&Bs[(sr + 128) * LDT + sc]) = b2;
        *reinterpret_cast<uint4*>(&Bs[(sr + 192) * LDT + sc]) = b3;
        __syncthreads();
        if (k0 + 32 < 256) {
            a00 = *reinterpret_cast<const float4*>(pA0 + k0 + 32);
            a01 = *reinterpret_cast<const float4*>(pA0 + k0 + 36);
            a10 = *reinterpret_cast<const float4*>(pA1 + k0 + 32);
            a11 = *reinterpret_cast<const float4*>(pA1 + k0 + 36);
            b0  = *reinterpret_cast<const uint4*>(pB0 + k0 + 32);
            b1  = *reinterpret_cast<const uint4*>(pB1 + k0 + 32);
            b2  = *reinterpret_cast<const uint4*>(pB2 + k0 + 32);
            b3  = *reinterpret_cast<const uint4*>(pB3 + k0 + 32);
        }

        bf16x8v af[4], bfr[8];
        #pragma unroll
        for (int m = 0; m < 4; ++m) {
            int ar = wr * 64 + m * 16 + l15;
            bf16x4v lo = *reinterpret_cast<const bf16x4v*>(&As[ar * LDT + kg]);
            bf16x4v hi = *reinterpret_cast<const bf16x4v*>(&As[ar * LDT + kg + 16]);
            af[m] = __builtin_shufflevector(lo, hi, 0, 1, 2, 3, 4, 5, 6, 7);
        }
        #pragma unroll
        for (int n = 0; n < 8; ++n) {
            int br = wc * 128 + n * 16 + l15;
            bf16x4v lo = *reinterpret_cast<const bf16x4v*>(&Bs[br * LDT + kg]);
            bf16x4v hi = *reinterpret_cast<const bf16x4v*>(&Bs[br * LDT + kg + 16]);
            bfr[n] = __builtin_shufflevector(lo, hi, 0, 1, 2, 3, 4, 5, 6, 7);
        }
        #pragma unroll
        for (int m = 0; m < 4; ++m)
            #pragma unroll
            for (int n = 0; n < 8; ++n)
                acc[m][n] = __builtin_amdgcn_mfma_f32_16x16x32_bf16(af[m], bfr[n], acc[m][n], 0, 0, 0);
        __syncthreads();
    }

    #pragma unroll
    for (int m = 0; m < 4; ++m) {
        int grow_base = row0 + wr * 64 + m * 16 + kg;
        #pragma unroll
        for (int j = 0; j < 4; ++j) {
            int grow = grow_base + j;
            if (grow >= M) continue;
            #pragma unroll
            for (int n = 0; n < 8; ++n) {
                int gcol = col0 + wc * 128 + n * 16 + l15;
                if (gcol >= Nw) continue;
                outF[(size_t)grow * ldo + gcol] = acc[m][n][j];
            }
        }
    }
}

// ---- eh = tanh(BN_h(tmpBN[:,256:512]))[N_SS:] + hh1, bf16 row-padded -------
__global__ void make_ehb_bn_kernel(const float* __restrict__ tmpBN,
                                   const float* __restrict__ stats,
                                   const float* __restrict__ g, const float* __restrict__ be,
                                   const float* __restrict__ hh1,
                                   ushort* __restrict__ out, int Rp) {
    int i = blockIdx.x * blockDim.x + threadIdx.x;
    if (i >= Rp * 256) return;
    int r = i >> 8, c = i & 255;
    float v = 0.f;
    if (r < N_HH) {
        float invM = 1.0f / (float)N_SH;
        int j = 256 + c;
        float mean = stats[j] * invM;
        float var  = fmaxf(stats[512 + j] * invM - mean * mean, 0.f);
        float x = tmpBN[(size_t)(N_SS + r) * 512 + j];
        float y = tanhf((x - mean) * rsqrtf(var + 1e-5f) * g[c] + be[c]);
        v = y + hh1[(size_t)r * 256 + c];
    }
    out[i] = f2bf(v);
}

// ---------------- driver -----------------------------------------------------
extern "C" void kernel_launch(void* const* d_in, const int* in_sizes, int n_in,
                              void* d_out, int out_size, void* d_ws, size_t ws_size,
                              hipStream_t stream) {
    const int*   eiSH = (const int*)d_in[1];
    const int*   eiSS = (const int*)d_in[3];
    const int*   eiHH = (const int*)d_in[5];
    const float* P    = (const float*)d_in[6];
    const float* kg   = (const float*)d_in[7];
    const float* emb  = (const float*)d_in[8];
    const float* w_sh1  = (const float*)d_in[9];   const float* b_sh1  = (const float*)d_in[10];
    const float* w_sh2  = (const float*)d_in[11];  const float* b_sh2  = (const float*)d_in[12];
    const float* w_mlp1 = (const float*)d_in[13];  const float* b_mlp1 = (const float*)d_in[14];
    const float* g_bn1  = (const float*)d_in[15];  const float* be_bn1 = (const float*)d_in[16];
    const float* w_sh1h = (const float*)d_in[17];  const float* b_sh1h = (const float*)d_in[18];
    const float* w_sh2h = (const float*)d_in[19];  const float* b_sh2h = (const float*)d_in[20];
    const float* w_mlp1h= (const float*)d_in[21];  const float* b_mlp1h= (const float*)d_in[22];
    const float* g_bn1h = (const float*)d_in[23];  const float* be_bn1h= (const float*)d_in[24];
    const float* w_ss   = (const float*)d_in[25];  const float* b_ss   = (const float*)d_in[26];
    const float* w_hh   = (const float*)d_in[27];  const float* b_hh   = (const float*)d_in[28];
    const float* w_mlp  = (const float*)d_in[29];  const float* b_mlp  = (const float*)d_in[30];
    const float* g_si   = (const float*)d_in[31];  const float* be_si  = (const float*)d_in[32];
    float* out = (float*)d_out;

    const int E_SH = in_sizes[1] / 2;
    const int E_SS = in_sizes[3] / 2;
    const int E_HH = in_sizes[5] / 2;
    const int B    = in_sizes[6] / N_SS;      // 20000
    const int Mp   = ((B + 127) / 128) * 128; // 20096
    const int KP1  = 416;
    const int NP3  = 1024;                    // eh_b rows (256-col C3 tile needs 4x256)
    const int KSH  = 1216;
    const int KHH  = 832;
    const int HS_SH = (N_SH + 3) / 4;
    const int HS_SS = (N_SS + 3) / 4;
    const int HS_HH = (N_HH + 3) / 4;

    float* w = (float*)d_ws;
    size_t off = 0;
    auto alloc = [&](size_t n) { float* p = w + off; off += (n + 3) & ~(size_t)3; return p; };

    float* cntInv   = alloc(N_SH);
    float* statsCat = alloc(1024);
    float* statsC2  = alloc(512);
    ushort* HT      = (ushort*)alloc((size_t)128 * KSH / 2);
    ushort* HSST    = (ushort*)alloc((size_t)256 * KP1 / 2);
    ushort* HHHT    = (ushort*)alloc((size_t)256 * KHH / 2);
    ushort* eswT    = (ushort*)alloc((size_t)256 * KP1 / 2);
    float* W1cat   = alloc(64 * 128);
    float* b1cat   = alloc(128);
    float* W2bd    = alloc(128 * 128);
    float* b2cat   = alloc(128);
    float* WMbd    = alloc(128 * 512);
    float* bMcat   = alloc(512);
    ushort* adjb   = (ushort*)alloc((size_t)1280 * KSH / 2);
    ushort* adjSSb = (ushort*)alloc((size_t)512 * KP1 / 2);
    ushort* adjHHb = (ushort*)alloc((size_t)896 * KHH / 2);
    float* x2cat   = alloc((size_t)N_SH * 128);
    float* x9a2    = alloc((size_t)N_SH * 128);
    float* tmpBN   = alloc((size_t)N_SH * 512);
    float* ss1     = alloc((size_t)N_SS * 256);
    float* hh1     = alloc((size_t)N_HH * 256);
    float* xhh0    = alloc((size_t)N_HH * 91);
    ushort* eh_b   = (ushort*)alloc((size_t)NP3 * 256 / 2);
    float* regionA = alloc((size_t)Mp * 256);
    uint32_t* uSH  = (uint32_t*)regionA;
    uint32_t* uSS  = uSH + (size_t)N_SH * HS_SH;
    uint32_t* uHH  = uSS + (size_t)N_SS * HS_SS;
    size_t packed_words = (size_t)N_SH * HS_SH + (size_t)N_SS * HS_SS + (size_t)N_HH * HS_HH;
    float*  bufM   = regionA;
    float* regionB = alloc((size_t)Mp * 256);
    float*  partials = regionB;
    float*  pSS = regionB;
    float*  pHH = regionB + (size_t)4 * N_SS * 256;
    (void)ws_size; (void)n_in; (void)out_size;

    const int nZeroF = 1536;
    const int nZeroH = 128 * KSH + 256 * KP1 + 256 * KHH + 256 * KP1;

    auto gemmT = [&](const float* Am, const float* A2m, int lda1, int lda2,
                     const float* Bm, const float* bias,
                     ushort* oT, int ldt, int M, int N, int K,
                     const float* bnS, const float* bnG, const float* bnB, int bnM) {
        dim3 g((N + BN - 1) / BN, (M + BM - 1) / BM);
        gemm_kernel<<<g, 256, 0, stream>>>(Am, A2m, lda1, lda2, Bm, bias,
                                           nullptr, oT, ldt, M, N, K, nullptr, 0,
                                           bnS, bnG, bnB, bnM);
    };
    auto gemmF = [&](const float* Am, const float* Bm, const float* bias,
                     float* C, int M, int N, int K, float* st, int sstride) {
        dim3 g((N + BN - 1) / BN, (M + BM - 1) / BM);
        gemm_kernel<<<g, 256, 0, stream>>>(Am, nullptr, K, 0, Bm, bias,
                                           C, nullptr, 0, M, N, K, st, sstride,
                                           nullptr, nullptr, nullptr, 0);
    };
    auto splitk = [&](const ushort* Am, const ushort* Bm, int M, int Mtiles, int K, int lda,
                      int Ntot, int S, const float* rs, const float* embA, const float* prev,
                      float* outp) {
        dim3 g(Ntot / 128, Mtiles, S);
        mfma_splitk_kernel<<<g, 256, 0, stream>>>(Am, Bm, M, K, lda, 128, Ntot, partials);
        reduce_tanh_kernel<<<(M * Ntot + 255) / 256, 256, 0, stream>>>(
            partials, S, M, Ntot, rs, embA, prev, outp);
    };

    // ---- memset: packed tables only (rest zeroed in mega_prep) ----
    hipMemsetAsync(uSH, 0, packed_words * sizeof(uint32_t), stream);

    // ---- adjacency build (atomic floor: ~E x 32B memory-side traffic) ----
    {
        int Etot = E_SH + E_SS + E_HH;
        build_adj3_kernel<<<(Etot + 255) / 256, 256, 0, stream>>>(
            eiSH, E_SH, HS_SH, uSH, eiSS, E_SS, HS_SS, uSS, eiHH, E_HH, HS_HH, uHH);
    }
    // ---- mega-prep ----
    {
        int n1 = 1280 * KSH, n2 = 512 * KP1, n3 = 896 * KHH;
        long long tot = (long long)n1 + n2 + n3 + N_SH * 64 + 90880 + N_HH * 91
                        + nZeroF + nZeroH;
        mega_prep_kernel<<<(unsigned)((tot + 255) / 256), 256, 0, stream>>>(
            uSH, HS_SH, adjb, n1, KSH, uSS, HS_SS, adjSSb, n2, KP1,
            uHH, HS_HH, adjHHb, n3, KHH, cntInv,
            w_sh1, w_sh1h, b_sh1, b_sh1h, w_sh2, w_sh2h, b_sh2, b_sh2h,
            w_mlp1, w_mlp1h, b_mlp1, b_mlp1h,
            W1cat, b1cat, W2bd, b2cat, WMbd, bMcat,
            emb, kg, xhh0,
            statsCat, nZeroF, HT, nZeroH);
    }

    // ---- SS + HH linear layers (merged) ----
    {
        dim3 g(4, 13, 2);
        gemm_side_kernel<<<g, 256, 0, stream>>>(emb, w_ss, b_ss, HSST,
                                                xhh0, w_hh, b_hh, HHHT, KP1, KHH);
    }
    // ---- SS + HH adjacency SpMM (merged) ----
    {
        dim3 g(2, 7, 11);
        mfma_splitk_side_kernel<<<g, 256, 0, stream>>>(
            adjSSb, HSST, KP1, pSS, adjHHb, HHHT, KHH, pHH);
        int totE = N_SS * 256 + N_HH * 256;
        reduce_side_kernel<<<(totE + 255) / 256, 256, 0, stream>>>(pSS, ss1, pHH, hh1);
    }

    // ---- SH layers (fused branches) ----
    gemmT(emb, nullptr, 64, 0, W1cat, b1cat, HT, KSH, N_SH, 128, 64,
          nullptr, nullptr, nullptr, 0);
    splitk(adjb, HT, N_SH, 10, KSH, KSH, 128, 10, cntInv, nullptr, nullptr, x2cat);
    gemmT(x2cat, nullptr, 128, 0, W2bd, b2cat, HT, KSH, N_SH, 128, 128,
          nullptr, nullptr, nullptr, 0);
    splitk(adjb, HT, N_SH, 10, KSH, KSH, 128, 10, cntInv, emb, x2cat, x9a2);
    gemmF(x9a2, WMbd, bMcat, tmpBN, N_SH, 512, 128, statsCat, 512);

    // ---- eh operand (BN+tanh fused) ----
    make_ehb_bn_kernel<<<(NP3 * 256 + 255) / 256, 256, 0, stream>>>(
        tmpBN, statsCat, g_bn1h, be_bn1h, hh1, eh_b, NP3);

    // ---- prescription path ----
    gemmT(tmpBN, ss1, 512, 256, w_mlp, nullptr, eswT, KP1, N_SS, 256, 256,
          statsCat, g_bn1, be_bn1, N_SH);
    {
        dim3 g(2, (B + 127) / 128);
        mfma_c1_kernel<<<g, 256, 0, stream>>>(P, eswT, B, b_mlp, bufM, statsC2);
    }
    {
        dim3 g(4, (B + 127) / 128);
        mfma_c3_kernel<<<g, 256, 0, stream>>>(bufM, eh_b, B, N_HH, statsC2, g_si, be_si, out, N_HH);
    }
}

// Round 16
// 295.371 us; speedup vs baseline: 1.0138x; 1.0138x over previous
//
#include <hip/hip_runtime.h>
#include <cstddef>
#include <cstdint>

#define N_SH 1195
#define N_SS 390
#define N_HH 805
#define DIM  64

typedef __bf16 bf16_t;
typedef bf16_t bf16x4v __attribute__((ext_vector_type(4)));
typedef bf16_t bf16x8v __attribute__((ext_vector_type(8)));
typedef float f32x4 __attribute__((ext_vector_type(4)));

__device__ inline ushort f2bf(float f) {
    union { float f; uint32_t u; } c; c.f = f;
    uint32_t u = c.u;
    u += 0x7FFFu + ((u >> 16) & 1u);
    return (ushort)(u >> 16);
}

// bijective XCD swizzle (m204)
__device__ inline void xcd_swizzle(int gx, int gy, int& bx, int& by) {
    int nwg = gx * gy;
    int lin = by * gx + bx;
    int q = nwg >> 3, r = nwg & 7;
    int xcd = lin & 7, idx = lin >> 3;
    int nt = (xcd < r ? xcd * (q + 1) : r * (q + 1) + (xcd - r) * q) + idx;
    by = nt / gx; bx = nt % gx;
}

// ---------------- adjacency build: packed 4x8-bit counters, all 3 graphs ----
__global__ void build_adj3_kernel(
    const int* __restrict__ e1, int E1, int hs1, uint32_t* __restrict__ T1,
    const int* __restrict__ e2, int E2, int hs2, uint32_t* __restrict__ T2,
    const int* __restrict__ e3, int E3, int hs3, uint32_t* __restrict__ T3)
{
    int i = blockIdx.x * blockDim.x + threadIdx.x;
    if (i < E1) {
        int src = e1[i], dst = e1[E1 + i];
        atomicAdd(&T1[(size_t)dst * hs1 + (src >> 2)], 1u << ((src & 3) * 8));
    } else if (i < E1 + E2) {
        int j = i - E1;
        int src = e2[j], dst = e2[E2 + j];
        atomicAdd(&T2[(size_t)dst * hs2 + (src >> 2)], 1u << ((src & 3) * 8));
    } else if (i < E1 + E2 + E3) {
        int j = i - E1 - E2;
        int src = e3[j], dst = e3[E3 + j];
        atomicAdd(&T3[(size_t)dst * hs3 + (src >> 2)], 1u << ((src & 3) * 8));
    }
}

__device__ inline void unpack_one(const uint32_t* __restrict__ T, int R, int C,
                                  int hs, ushort* __restrict__ out, int Cp, int i) {
    int r = i / Cp, c = i % Cp;
    float v = 0.f;
    if (r < R && c < C) {
        uint32_t w = T[(size_t)r * hs + (c >> 2)];
        v = (float)((w >> ((c & 3) * 8)) & 0xFFu);
    }
    out[i] = f2bf(v);
}

// mega-prep: unpack adj + rowsum + cat weights + concat_hh + zero scratch
__global__ void mega_prep_kernel(
    const uint32_t* __restrict__ T1, int hs1, ushort* __restrict__ o1, int n1, int Cp1,
    const uint32_t* __restrict__ T2, int hs2, ushort* __restrict__ o2, int n2, int Cp2,
    const uint32_t* __restrict__ T3, int hs3, ushort* __restrict__ o3, int n3, int Cp3,
    float* __restrict__ cntInv,
    const float* __restrict__ w_sh1, const float* __restrict__ w_sh1h,
    const float* __restrict__ b_sh1, const float* __restrict__ b_sh1h,
    const float* __restrict__ w_sh2, const float* __restrict__ w_sh2h,
    const float* __restrict__ b_sh2, const float* __restrict__ b_sh2h,
    const float* __restrict__ w_mlp1, const float* __restrict__ w_mlp1h,
    const float* __restrict__ b_mlp1, const float* __restrict__ b_mlp1h,
    float* __restrict__ W1cat, float* __restrict__ b1cat,
    float* __restrict__ W2bd,  float* __restrict__ b2cat,
    float* __restrict__ WMbd,  float* __restrict__ bMcat,
    const float* __restrict__ emb, const float* __restrict__ kg,
    float* __restrict__ xhh0,
    float* __restrict__ zeroF, int nZeroF,
    ushort* __restrict__ zeroH, int nZeroH)
{
    int i = blockIdx.x * blockDim.x + threadIdx.x;
    if (i < n1) { unpack_one(T1, N_SH, N_SH, hs1, o1, Cp1, i); return; }
    i -= n1;
    if (i < n2) { unpack_one(T2, N_SS, N_SS, hs2, o2, Cp2, i); return; }
    i -= n2;
    if (i < n3) { unpack_one(T3, N_HH, N_HH, hs3, o3, Cp3, i); return; }
    i -= n3;
    if (i < N_SH * 64) {
        int row = i >> 6, lane = i & 63;
        const uint32_t* p = T1 + (size_t)row * hs1;
        uint32_t s = 0;
        for (int c = lane; c < hs1; c += 64) {
            uint32_t w0 = p[c];
            s += (w0 & 0xFFu) + ((w0 >> 8) & 0xFFu) + ((w0 >> 16) & 0xFFu) + (w0 >> 24);
        }
        for (int off = 32; off > 0; off >>= 1) s += __shfl_down(s, off);
        if (lane == 0) cntInv[row] = 1.0f / fmaxf((float)s, 1.0f);
        return;
    }
    i -= N_SH * 64;
    if (i < 64 * 128) {
        int k = i >> 7, j = i & 127;
        W1cat[i] = (j < 64) ? w_sh1[k * 64 + j] : w_sh1h[k * 64 + (j - 64)];
        return;
    }
    i -= 64 * 128;
    if (i < 128) { b1cat[i] = (i < 64) ? b_sh1[i] : b_sh1h[i - 64]; return; }
    i -= 128;
    if (i < 128 * 128) {
        int k = i >> 7, j = i & 127;
        float v = 0.f;
        if (k < 64 && j < 64) v = w_sh2[k * 64 + j];
        else if (k >= 64 && j >= 64) v = w_sh2h[(k - 64) * 64 + (j - 64)];
        W2bd[i] = v;
        return;
    }
    i -= 128 * 128;
    if (i < 128) { b2cat[i] = (i < 64) ? b_sh2[i] : b_sh2h[i - 64]; return; }
    i -= 128;
    if (i < 128 * 512) {
        int k = i >> 9, j = i & 511;
        float v = 0.f;
        if (j < 256) { if (k < 64) v = w_mlp1[k * 256 + j]; }
        else         { if (k >= 64) v = w_mlp1h[(k - 64) * 256 + (j - 256)]; }
        WMbd[i] = v;
        return;
    }
    i -= 128 * 512;
    if (i < 512) { bMcat[i] = (i < 256) ? b_mlp1[i] : b_mlp1h[i - 256]; return; }
    i -= 512;
    if (i < N_HH * 91) {
        int r = i / 91, c = i % 91;
        xhh0[i] = (c < DIM) ? emb[r * DIM + c] : kg[r * 27 + (c - DIM)];
        return;
    }
    i -= N_HH * 91;
    if (i < nZeroF) { zeroF[i] = 0.f; return; }
    i -= nZeroF;
    if (i < nZeroH) { zeroH[i] = 0; }
}

// -------- fp32 GEMM body (device fn): A2 add, BN-on-A, transposed-bf16 out --
#define BM 64
#define BN 64
#define BK 16

__device__ __forceinline__ void gemm_body(
    const float* __restrict__ A, const float* __restrict__ A2, int ldaA, int ldaA2,
    const float* __restrict__ B, const float* __restrict__ bias,
    float* __restrict__ C, ushort* __restrict__ outT, int ldt,
    int M, int N, int K, float* __restrict__ statsOut, int statsStride,
    const float* __restrict__ bnStats, const float* __restrict__ bnG,
    const float* __restrict__ bnBe, int bnM,
    int bx, int by, int tid,
    float* __restrict__ AsBuf, float* __restrict__ BsBuf,
    float* __restrict__ cs, float* __restrict__ sA, float* __restrict__ tA)
{
    const int row0 = by * BM;
    const int col0 = bx * BN;
    const int tr  = (tid >> 4) << 2;
    const int tc  = (tid & 15) << 2;
    const int lar = tid >> 2;
    const int lac = (tid & 3) << 2;
    const int lbr = tid >> 4;
    const int lbc = (tid & 15) << 2;

    if (bnStats) {
        float invM = 1.0f / (float)bnM;
        float mean = bnStats[tid] * invM;
        float var  = fmaxf(bnStats[512 + tid] * invM - mean * mean, 0.f);
        float scv  = bnG[tid] * rsqrtf(var + 1e-5f);
        sA[tid] = scv;
        tA[tid] = bnBe[tid] - mean * scv;
        __syncthreads();
    }

    float acc[4][4] = {{0.f}};

    for (int k0 = 0; k0 < K; k0 += BK) {
        const int gr = row0 + lar;
        #pragma unroll
        for (int i = 0; i < 4; ++i) {
            int gk = k0 + lac + i;
            float v = 0.f;
            if (gr < M && gk < K) {
                v = A[(size_t)gr * ldaA + gk];
                if (bnStats) v = tanhf(v * sA[gk] + tA[gk]);
                if (A2) v += A2[(size_t)gr * ldaA2 + gk];
            }
            AsBuf[(lac + i) * (BM + 4) + lar] = v;
        }
        const int gk = k0 + lbr;
        const float* Bp = B + (size_t)gk * N + col0 + lbc;
        #pragma unroll
        for (int i = 0; i < 4; ++i) {
            int gc = col0 + lbc + i;
            BsBuf[lbr * BN + lbc + i] = (gk < K && gc < N) ? Bp[i] : 0.f;
        }
        __syncthreads();
        #pragma unroll
        for (int kk = 0; kk < BK; ++kk) {
            float4 a = *reinterpret_cast<const float4*>(&AsBuf[kk * (BM + 4) + tr]);
            float4 b = *reinterpret_cast<const float4*>(&BsBuf[kk * BN + tc]);
            acc[0][0] += a.x * b.x; acc[0][1] += a.x * b.y; acc[0][2] += a.x * b.z; acc[0][3] += a.x * b.w;
            acc[1][0] += a.y * b.x; acc[1][1] += a.y * b.y; acc[1][2] += a.y * b.z; acc[1][3] += a.y * b.w;
            acc[2][0] += a.z * b.x; acc[2][1] += a.z * b.y; acc[2][2] += a.z * b.z; acc[2][3] += a.z * b.w;
            acc[3][0] += a.w * b.x; acc[3][1] += a.w * b.y; acc[3][2] += a.w * b.z; acc[3][3] += a.w * b.w;
        }
        __syncthreads();
    }

    float ls[4] = {0.f, 0.f, 0.f, 0.f}, lq[4] = {0.f, 0.f, 0.f, 0.f};
    #pragma unroll
    for (int i = 0; i < 4; ++i) {
        int gr = row0 + tr + i;
        if (gr >= M) continue;
        #pragma unroll
        for (int j = 0; j < 4; ++j) {
            int gc = col0 + tc + j;
            if (gc >= N) continue;
            float v = acc[i][j];
            if (bias) v += bias[gc];
            if (outT) outT[(size_t)gc * ldt + gr] = f2bf(v);
            else      C[(size_t)gr * N + gc] = v;
            ls[j] += v; lq[j] += v * v;
        }
    }

    if (statsOut) {
        if (tid < 128) cs[tid] = 0.f;
        __syncthreads();
        #pragma unroll
        for (int j = 0; j < 4; ++j) {
            atomicAdd(&cs[tc + j], ls[j]);
            atomicAdd(&cs[64 + tc + j], lq[j]);
        }
        __syncthreads();
        if (tid < 64) {
            atomicAdd(&statsOut[col0 + tid], cs[tid]);
            atomicAdd(&statsOut[statsStride + col0 + tid], cs[64 + tid]);
        }
    }
}

__global__ __launch_bounds__(256) void gemm_kernel(
    const float* __restrict__ A, const float* __restrict__ A2, int ldaA, int ldaA2,
    const float* __restrict__ B, const float* __restrict__ bias,
    float* __restrict__ C, ushort* __restrict__ outT, int ldt,
    int M, int N, int K, float* __restrict__ statsOut, int statsStride,
    const float* __restrict__ bnStats, const float* __restrict__ bnG,
    const float* __restrict__ bnBe, int bnM)
{
    __shared__ float As[BK * (BM + 4)];
    __shared__ float Bs[BK * BN];
    __shared__ float cs[128];
    __shared__ float sA[256], tA[256];
    gemm_body(A, A2, ldaA, ldaA2, B, bias, C, outT, ldt, M, N, K,
              statsOut, statsStride, bnStats, bnG, bnBe, bnM,
              blockIdx.x, blockIdx.y, threadIdx.x, As, Bs, cs, sA, tA);
}

// SS (z=0) + HH (z=1) linear layers in one launch
__global__ __launch_bounds__(256) void gemm_side_kernel(
    const float* __restrict__ emb, const float* __restrict__ w_ss,
    const float* __restrict__ b_ss, ushort* __restrict__ HSST,
    const float* __restrict__ xhh0, const float* __restrict__ w_hh,
    const float* __restrict__ b_hh, ushort* __restrict__ HHHT,
    int KP1v, int KHHv)
{
    __shared__ float As[BK * (BM + 4)];
    __shared__ float Bs[BK * BN];
    __shared__ float cs[128];
    __shared__ float sA[256], tA[256];
    if (blockIdx.z == 0) {
        if (blockIdx.y >= 7) return;
        gemm_body(emb, nullptr, 64, 0, w_ss, b_ss, nullptr, HSST, KP1v,
                  N_SS, 256, 64, nullptr, 0, nullptr, nullptr, nullptr, 0,
                  blockIdx.x, blockIdx.y, threadIdx.x, As, Bs, cs, sA, tA);
    } else {
        gemm_body(xhh0, nullptr, 91, 0, w_hh, b_hh, nullptr, HHHT, KHHv,
                  N_HH, 256, 91, nullptr, 0, nullptr, nullptr, nullptr, 0,
                  blockIdx.x, blockIdx.y, threadIdx.x, As, Bs, cs, sA, tA);
    }
}

// ---------------- split-K MFMA body ------------------------------------------
#define LDT 40
#define OLW 132

__device__ __forceinline__ void splitk_body(
    const ushort* __restrict__ A, const ushort* __restrict__ Bt,
    int M, int K, int lda, int kChunk, int Ntot,
    float* __restrict__ part, int bx, int by, int bz, int tid,
    ushort* __restrict__ As, ushort* __restrict__ Bs)
{
    const int row0 = by * 128;
    const int col0 = bx * 128;
    const int wid  = tid >> 6, lane = tid & 63;
    const int wr = wid >> 1, wc = wid & 1;
    const int l15 = lane & 15, lg = lane >> 4;
    const int kg = lg * 4;
    const int sr = tid >> 2;
    const int sc = (tid & 3) * 8;

    const int k0s = bz * kChunk;
    const int k0e = (k0s + kChunk < K) ? k0s + kChunk : K;

    const ushort* pA0 = A  + (size_t)(row0 + sr)      * lda + sc;
    const ushort* pA1 = A  + (size_t)(row0 + sr + 64) * lda + sc;
    const ushort* pB0 = Bt + (size_t)(col0 + sr)      * lda + sc;
    const ushort* pB1 = Bt + (size_t)(col0 + sr + 64) * lda + sc;

    uint4 ra0 = *reinterpret_cast<const uint4*>(pA0 + k0s);
    uint4 ra1 = *reinterpret_cast<const uint4*>(pA1 + k0s);
    uint4 rb0 = *reinterpret_cast<const uint4*>(pB0 + k0s);
    uint4 rb1 = *reinterpret_cast<const uint4*>(pB1 + k0s);

    f32x4 acc[4][4];
    #pragma unroll
    for (int m = 0; m < 4; ++m)
        #pragma unroll
        for (int n = 0; n < 4; ++n) acc[m][n] = (f32x4)0.f;

    for (int k0 = k0s; k0 < k0e; k0 += 32) {
        *reinterpret_cast<uint4*>(&As[sr * LDT + sc])        = ra0;
        *reinterpret_cast<uint4*>(&As[(sr + 64) * LDT + sc]) = ra1;
        *reinterpret_cast<uint4*>(&Bs[sr * LDT + sc])        = rb0;
        *reinterpret_cast<uint4*>(&Bs[(sr + 64) * LDT + sc]) = rb1;
        __syncthreads();
        if (k0 + 32 < k0e) {
            ra0 = *reinterpret_cast<const uint4*>(pA0 + k0 + 32);
            ra1 = *reinterpret_cast<const uint4*>(pA1 + k0 + 32);
            rb0 = *reinterpret_cast<const uint4*>(pB0 + k0 + 32);
            rb1 = *reinterpret_cast<const uint4*>(pB1 + k0 + 32);
        }

        bf16x8v af[4], bfr[4];
        #pragma unroll
        for (int m = 0; m < 4; ++m) {
            int ar = wr * 64 + m * 16 + l15;
            bf16x4v lo = *reinterpret_cast<const bf16x4v*>(&As[ar * LDT + kg]);
            bf16x4v hi = *reinterpret_cast<const bf16x4v*>(&As[ar * LDT + kg + 16]);
            af[m] = __builtin_shufflevector(lo, hi, 0, 1, 2, 3, 4, 5, 6, 7);
        }
        #pragma unroll
        for (int n = 0; n < 4; ++n) {
            int br = wc * 64 + n * 16 + l15;
            bf16x4v lo = *reinterpret_cast<const bf16x4v*>(&Bs[br * LDT + kg]);
            bf16x4v hi = *reinterpret_cast<const bf16x4v*>(&Bs[br * LDT + kg + 16]);
            bfr[n] = __builtin_shufflevector(lo, hi, 0, 1, 2, 3, 4, 5, 6, 7);
        }
        #pragma unroll
        for (int m = 0; m < 4; ++m)
            #pragma unroll
            for (int n = 0; n < 4; ++n)
                acc[m][n] = __builtin_amdgcn_mfma_f32_16x16x32_bf16(af[m], bfr[n], acc[m][n], 0, 0, 0);
        __syncthreads();
    }

    float* pslab = part + (size_t)bz * M * Ntot;
    #pragma unroll
    for (int m = 0; m < 4; ++m) {
        int grow_base = row0 + wr * 64 + m * 16 + kg;
        #pragma unroll
        for (int j = 0; j < 4; ++j) {
            int grow = grow_base + j;
            if (grow >= M) continue;
            #pragma unroll
            for (int n = 0; n < 4; ++n) {
                int gcol = col0 + wc * 64 + n * 16 + l15;
                pslab[(size_t)grow * Ntot + gcol] = acc[m][n][j];
            }
        }
    }
}

__global__ __launch_bounds__(256) void mfma_splitk_kernel(
    const ushort* __restrict__ A, const ushort* __restrict__ Bt,
    int M, int K, int lda, int kChunk, int Ntot, float* __restrict__ part)
{
    __shared__ __align__(16) ushort As[128 * LDT];
    __shared__ __align__(16) ushort Bs[128 * LDT];
    splitk_body(A, Bt, M, K, lda, kChunk, Ntot, part,
                blockIdx.x, blockIdx.y, blockIdx.z, threadIdx.x, As, Bs);
}

// SS (z<4) + HH (z>=4) splitk in one launch
__global__ __launch_bounds__(256) void mfma_splitk_side_kernel(
    const ushort* __restrict__ adjSS, const ushort* __restrict__ HSST, int KP1v,
    float* __restrict__ pSS,
    const ushort* __restrict__ adjHH, const ushort* __restrict__ HHHT, int KHHv,
    float* __restrict__ pHH)
{
    __shared__ __align__(16) ushort As[128 * LDT];
    __shared__ __align__(16) ushort Bs[128 * LDT];
    if (blockIdx.z < 4) {
        if (blockIdx.y >= 4) return;
        splitk_body(adjSS, HSST, N_SS, KP1v, KP1v, 128, 256, pSS,
                    blockIdx.x, blockIdx.y, blockIdx.z, threadIdx.x, As, Bs);
    } else {
        splitk_body(adjHH, HHHT, N_HH, KHHv, KHHv, 128, 256, pHH,
                    blockIdx.x, blockIdx.y, blockIdx.z - 4, threadIdx.x, As, Bs);
    }
}

// reduce partials; t = tanh(sum*rs). emb? out = (emb + prev + t)/3 : out = t
__global__ void reduce_tanh_kernel(const float* __restrict__ part, int S, int M, int N,
                                   const float* __restrict__ rs,
                                   const float* __restrict__ emb,
                                   const float* __restrict__ prev,
                                   float* __restrict__ out) {
    int i = blockIdx.x * blockDim.x + threadIdx.x;
    if (i >= M * N) return;
    int r = i / N, j = i - r * N;
    float s = 0.f;
    for (int z = 0; z < S; ++z) s += part[(size_t)z * M * N + i];
    if (rs) s *= rs[r];
    float t = tanhf(s);
    if (emb) out[i] = (emb[r * 64 + (j & 63)] + prev[i] + t) * (1.0f / 3.0f);
    else     out[i] = t;
}

// merged SS+HH reduce
__global__ void reduce_side_kernel(const float* __restrict__ pSS, float* __restrict__ ss1,
                                   const float* __restrict__ pHH, float* __restrict__ hh1) {
    int i = blockIdx.x * blockDim.x + threadIdx.x;
    const int nSS = N_SS * 256;
    const int nHH = N_HH * 256;
    if (i < nSS) {
        float s = 0.f;
        for (int z = 0; z < 4; ++z) s += pSS[(size_t)z * nSS + i];
        ss1[i] = tanhf(s);
        return;
    }
    i -= nSS;
    if (i < nHH) {
        float s = 0.f;
        for (int z = 0; z < 7; ++z) s += pHH[(size_t)z * nHH + i];
        hh1[i] = tanhf(s);
    }
}

// ---------------- C1': bufM = (P @ D^T)·(1/rowsum(P)) + b_mlp, BN stats -----
__device__ inline void loadP8(const float* __restrict__ rowp, int c0, bool rv,
                              float* a, float& s) {
    if (rv && c0 + 8 <= N_SS) {
        float2 x0 = *reinterpret_cast<const float2*>(rowp + c0);
        float2 x1 = *reinterpret_cast<const float2*>(rowp + c0 + 2);
        float2 x2 = *reinterpret_cast<const float2*>(rowp + c0 + 4);
        float2 x3 = *reinterpret_cast<const float2*>(rowp + c0 + 6);
        a[0] = x0.x; a[1] = x0.y; a[2] = x1.x; a[3] = x1.y;
        a[4] = x2.x; a[5] = x2.y; a[6] = x3.x; a[7] = x3.y;
    } else {
        #pragma unroll
        for (int i = 0; i < 8; ++i) a[i] = (rv && (c0 + i) < N_SS) ? rowp[c0 + i] : 0.f;
    }
    #pragma unroll
    for (int i = 0; i < 8; ++i) s += a[i];
}

__global__ __launch_bounds__(256) void mfma_c1_kernel(
    const float* __restrict__ Pm, const ushort* __restrict__ Dt,
    int M, const float* __restrict__ bias,
    float* __restrict__ outF, float* __restrict__ statsOut)
{
    __shared__ __align__(16) uint8_t smemRaw[128 * LDT * 2 * 2];
    ushort* As = (ushort*)smemRaw;
    ushort* Bs = (ushort*)(smemRaw + 128 * LDT * 2);
    float*  oLds = (float*)smemRaw;
    __shared__ float sums[128];
    __shared__ float cs[256];
    const int tid  = threadIdx.x;
    int bx = blockIdx.x, by = blockIdx.y;
    xcd_swizzle(gridDim.x, gridDim.y, bx, by);
    const int row0 = by * 128;
    const int col0 = bx * 128;
    const int wid  = tid >> 6, lane = tid & 63;
    const int wr = wid >> 1, wc = wid & 1;
    const int l15 = lane & 15, lg = lane >> 4;
    const int kg = lg * 4;
    const int sr = tid >> 2;
    const int sc = (tid & 3) * 8;

    const float* pA0 = Pm + (size_t)(row0 + sr)      * N_SS;
    const float* pA1 = Pm + (size_t)(row0 + sr + 64) * N_SS;
    const bool rv0 = (row0 + sr)      < M;
    const bool rv1 = (row0 + sr + 64) < M;
    const ushort* pB0 = Dt + (size_t)(col0 + sr)      * 416 + sc;
    const ushort* pB1 = Dt + (size_t)(col0 + sr + 64) * 416 + sc;

    float a0[8], a1[8];
    float s0 = 0.f, s1 = 0.f;
    loadP8(pA0, sc, rv0, a0, s0);
    loadP8(pA1, sc, rv1, a1, s1);
    uint4 b0 = *reinterpret_cast<const uint4*>(pB0);
    uint4 b1 = *reinterpret_cast<const uint4*>(pB1);

    f32x4 acc[4][4];
    #pragma unroll
    for (int m = 0; m < 4; ++m)
        #pragma unroll
        for (int n = 0; n < 4; ++n) acc[m][n] = (f32x4)0.f;

    for (int k0 = 0; k0 < 416; k0 += 32) {
        {
            bf16_t h[8];
            #pragma unroll
            for (int i = 0; i < 8; ++i) h[i] = (bf16_t)a0[i];
            *reinterpret_cast<uint4*>(&As[sr * LDT + sc]) = *reinterpret_cast<const uint4*>(h);
            #pragma unroll
            for (int i = 0; i < 8; ++i) h[i] = (bf16_t)a1[i];
            *reinterpret_cast<uint4*>(&As[(sr + 64) * LDT + sc]) = *reinterpret_cast<const uint4*>(h);
        }
        *reinterpret_cast<uint4*>(&Bs[sr * LDT + sc])        = b0;
        *reinterpret_cast<uint4*>(&Bs[(sr + 64) * LDT + sc]) = b1;
        __syncthreads();
        if (k0 + 32 < 416) {
            loadP8(pA0, k0 + 32 + sc, rv0, a0, s0);
            loadP8(pA1, k0 + 32 + sc, rv1, a1, s1);
            b0 = *reinterpret_cast<const uint4*>(pB0 + k0 + 32);
            b1 = *reinterpret_cast<const uint4*>(pB1 + k0 + 32);
        }

        bf16x8v af[4], bfr[4];
        #pragma unroll
        for (int m = 0; m < 4; ++m) {
            int ar = wr * 64 + m * 16 + l15;
            bf16x4v lo = *reinterpret_cast<const bf16x4v*>(&As[ar * LDT + kg]);
            bf16x4v hi = *reinterpret_cast<const bf16x4v*>(&As[ar * LDT + kg + 16]);
            af[m] = __builtin_shufflevector(lo, hi, 0, 1, 2, 3, 4, 5, 6, 7);
        }
        #pragma unroll
        for (int n = 0; n < 4; ++n) {
            int br = wc * 64 + n * 16 + l15;
            bf16x4v lo = *reinterpret_cast<const bf16x4v*>(&Bs[br * LDT + kg]);
            bf16x4v hi = *reinterpret_cast<const bf16x4v*>(&Bs[br * LDT + kg + 16]);
            bfr[n] = __builtin_shufflevector(lo, hi, 0, 1, 2, 3, 4, 5, 6, 7);
        }
        #pragma unroll
        for (int m = 0; m < 4; ++m)
            #pragma unroll
            for (int n = 0; n < 4; ++n)
                acc[m][n] = __builtin_amdgcn_mfma_f32_16x16x32_bf16(af[m], bfr[n], acc[m][n], 0, 0, 0);
        __syncthreads();
    }

    if (tid < 128) sums[tid] = 0.f;
    if (tid < 256) cs[tid] = 0.f;
    __syncthreads();
    atomicAdd(&sums[sr], s0);
    atomicAdd(&sums[sr + 64], s1);
    __syncthreads();

    float ls[4] = {0.f, 0.f, 0.f, 0.f}, lq[4] = {0.f, 0.f, 0.f, 0.f};
    #pragma unroll
    for (int m = 0; m < 4; ++m) {
        int lr_base = wr * 64 + m * 16 + kg;
        #pragma unroll
        for (int j = 0; j < 4; ++j) {
            int lr = lr_base + j;
            int grow = row0 + lr;
            float t = sums[lr];
            float inv = (t != 0.f) ? 1.0f / t : 0.f;
            #pragma unroll
            for (int n = 0; n < 4; ++n) {
                int gcol = col0 + wc * 64 + n * 16 + l15;
                float v = acc[m][n][j] * inv + bias[gcol];
                acc[m][n][j] = v;
                if (grow < M) { ls[n] += v; lq[n] += v * v; }
            }
        }
    }

    #pragma unroll
    for (int n = 0; n < 4; ++n) {
        int lc = wc * 64 + n * 16 + l15;
        atomicAdd(&cs[lc], ls[n]);
        atomicAdd(&cs[128 + lc], lq[n]);
    }
    __syncthreads();
    if (tid < 128) {
        atomicAdd(&statsOut[col0 + tid], cs[tid]);
        atomicAdd(&statsOut[256 + col0 + tid], cs[128 + tid]);
    }

    for (int m = 0; m < 4; ++m) {
        __syncthreads();
        #pragma unroll
        for (int n = 0; n < 4; ++n)
            #pragma unroll
            for (int j = 0; j < 4; ++j)
                oLds[(wr * 16 + kg + j) * OLW + wc * 64 + n * 16 + l15] = acc[m][n][j];
        __syncthreads();
        #pragma unroll
        for (int rr = 0; rr < 8; ++rr) {
            int lrow = wid * 8 + rr;
            int band = lrow >> 4;
            int r16  = lrow & 15;
            int grow = row0 + band * 64 + m * 16 + r16;
            if (grow < M) {
                float v0 = oLds[lrow * OLW + lane];
                float v1 = oLds[lrow * OLW + 64 + lane];
                outF[(size_t)grow * 256 + col0 + lane]      = v0;
                outF[(size_t)grow * 256 + col0 + 64 + lane] = v1;
            }
        }
    }
}

// ------ C3: A = relu(BN(bufM)), depth-1 prefetch, coalesced epilogue --------
__global__ __launch_bounds__(256) void mfma_c3_kernel(
    const float* __restrict__ Abuf, const ushort* __restrict__ Bt,
    int M, int Nw,
    const float* __restrict__ stats, const float* __restrict__ g,
    const float* __restrict__ be,
    float* __restrict__ outF, int ldo)
{
    __shared__ __align__(16) uint8_t smemRaw[128 * LDT * 2 * 2];
    ushort* As = (ushort*)smemRaw;
    ushort* Bs = (ushort*)(smemRaw + 128 * LDT * 2);
    float*  oLds = (float*)smemRaw;
    __shared__ float sscale[256], sshift[256];
    const int tid  = threadIdx.x;
    int bx = blockIdx.x, by = blockIdx.y;
    xcd_swizzle(gridDim.x, gridDim.y, bx, by);
    const int row0 = by * 128;
    const int col0 = bx * 128;
    const int wid  = tid >> 6, lane = tid & 63;
    const int wr = wid >> 1, wc = wid & 1;
    const int l15 = lane & 15, lg = lane >> 4;
    const int kg = lg * 4;
    const int sr = tid >> 2;
    const int sc = (tid & 3) * 8;

    if (tid < 256) {
        float invM = 1.0f / (float)M;
        float mean = stats[tid] * invM;
        float var  = fmaxf(stats[256 + tid] * invM - mean * mean, 0.f);
        float scv  = g[tid] * rsqrtf(var + 1e-5f);
        sscale[tid] = scv;
        sshift[tid] = be[tid] - mean * scv;
    }
    __syncthreads();

    const float*  pA0 = Abuf + (size_t)(row0 + sr)      * 256 + sc;
    const float*  pA1 = Abuf + (size_t)(row0 + sr + 64) * 256 + sc;
    const ushort* pB0 = Bt + (size_t)(col0 + sr)        * 256 + sc;
    const ushort* pB1 = Bt + (size_t)(col0 + sr + 64)   * 256 + sc;

    float4 a00 = *reinterpret_cast<const float4*>(pA0);
    float4 a01 = *reinterpret_cast<const float4*>(pA0 + 4);
    float4 a10 = *reinterpret_cast<const float4*>(pA1);
    float4 a11 = *reinterpret_cast<const float4*>(pA1 + 4);
    uint4  b0  = *reinterpret_cast<const uint4*>(pB0);
    uint4  b1  = *reinterpret_cast<const uint4*>(pB1);

    f32x4 acc[4][4];
    #pragma unroll
    for (int m = 0; m < 4; ++m)
        #pragma unroll
        for (int n = 0; n < 4; ++n) acc[m][n] = (f32x4)0.f;

    for (int k0 = 0; k0 < 256; k0 += 32) {
        float s8[8], t8[8];
        #pragma unroll
        for (int i = 0; i < 8; ++i) { s8[i] = sscale[k0 + sc + i]; t8[i] = sshift[k0 + sc + i]; }
        {
            bf16_t h[8];
            h[0] = (bf16_t)fmaxf(a00.x * s8[0] + t8[0], 0.f);
            h[1] = (bf16_t)fmaxf(a00.y * s8[1] + t8[1], 0.f);
            h[2] = (bf16_t)fmaxf(a00.z * s8[2] + t8[2], 0.f);
            h[3] = (bf16_t)fmaxf(a00.w * s8[3] + t8[3], 0.f);
            h[4] = (bf16_t)fmaxf(a01.x * s8[4] + t8[4], 0.f);
            h[5] = (bf16_t)fmaxf(a01.y * s8[5] + t8[5], 0.f);
            h[6] = (bf16_t)fmaxf(a01.z * s8[6] + t8[6], 0.f);
            h[7] = (bf16_t)fmaxf(a01.w * s8[7] + t8[7], 0.f);
            *reinterpret_cast<uint4*>(&As[sr * LDT + sc]) = *reinterpret_cast<const uint4*>(h);
            h[0] = (bf16_t)fmaxf(a10.x * s8[0] + t8[0], 0.f);
            h[1] = (bf16_t)fmaxf(a10.y * s8[1] + t8[1], 0.f);
            h[2] = (bf16_t)fmaxf(a10.z * s8[2] + t8[2], 0.f);
            h[3] = (bf16_t)fmaxf(a10.w * s8[3] + t8[3], 0.f);
            h[4] = (bf16_t)fmaxf(a11.x * s8[4] + t8[4], 0.f);
            h[5] = (bf16_t)fmaxf(a11.y * s8[5] + t8[5], 0.f);
            h[6] = (bf16_t)fmaxf(a11.z * s8[6] + t8[6], 0.f);
            h[7] = (bf16_t)fmaxf(a11.w * s8[7] + t8[7], 0.f);
            *reinterpret_cast<uint4*>(&As[(sr + 64) * LDT + sc]) = *reinterpret_cast<const uint4*>(h);
        }
        *reinterpret_cast<uint4*>(&Bs[sr * LDT + sc])        = b0;
        *reinterpret_cast<uint4*>(&Bs[(sr + 64) * LDT + sc]) = b1;
        __syncthreads();
        if (k0 + 32 < 256) {
            a00 = *reinterpret_cast<const float4*>(pA0 + k0 + 32);
            a01 = *reinterpret_cast<const float4*>(pA0 + k0 + 36);
            a10 = *reinterpret_cast<const float4*>(pA1 + k0 + 32);
            a11 = *reinterpret_cast<const float4*>(pA1 + k0 + 36);
            b0  = *reinterpret_cast<const uint4*>(pB0 + k0 + 32);
            b1  = *reinterpret_cast<const uint4*>(pB1 + k0 + 32);
        }

        bf16x8v af[4], bfr[4];
        #pragma unroll
        for (int m = 0; m < 4; ++m) {
            int ar = wr * 64 + m * 16 + l15;
            bf16x4v lo = *reinterpret_cast<const bf16x4v*>(&As[ar * LDT + kg]);
            bf16x4v hi = *reinterpret_cast<const bf16x4v*>(&As[ar * LDT + kg + 16]);
            af[m] = __builtin_shufflevector(lo, hi, 0, 1, 2, 3, 4, 5, 6, 7);
        }
        #pragma unroll
        for (int n = 0; n < 4; ++n) {
            int br = wc * 64 + n * 16 + l15;
            bf16x4v lo = *reinterpret_cast<const bf16x4v*>(&Bs[br * LDT + kg]);
            bf16x4v hi = *reinterpret_cast<const bf16x4v*>(&Bs[br * LDT + kg + 16]);
            bfr[n] = __builtin_shufflevector(lo, hi, 0, 1, 2, 3, 4, 5, 6, 7);
        }
        #pragma unroll
        for (int m = 0; m < 4; ++m)
            #pragma unroll
            for (int n = 0; n < 4; ++n)
                acc[m][n] = __builtin_amdgcn_mfma_f32_16x16x32_bf16(af[m], bfr[n], acc[m][n], 0, 0, 0);
        __syncthreads();
    }

    for (int m = 0; m < 4; ++m) {
        __syncthreads();
        #pragma unroll
        for (int n = 0; n < 4; ++n)
            #pragma unroll
            for (int j = 0; j < 4; ++j)
                oLds[(wr * 16 + kg + j) * OLW + wc * 64 + n * 16 + l15] = acc[m][n][j];
        __syncthreads();
        #pragma unroll
        for (int rr = 0; rr < 8; ++rr) {
            int lrow = wid * 8 + rr;
            int band = lrow >> 4;
            int r16  = lrow & 15;
            int grow = row0 + band * 64 + m * 16 + r16;
            if (grow < M) {
                float v0 = oLds[lrow * OLW + lane];
                float v1 = oLds[lrow * OLW + 64 + lane];
                int gc0 = col0 + lane;
                int gc1 = col0 + 64 + lane;
                if (gc0 < Nw) outF[(size_t)grow * ldo + gc0] = v0;
                if (gc1 < Nw) outF[(size_t)grow * ldo + gc1] = v1;
            }
        }
    }
}

// ---- eh = tanh(BN_h(tmpBN[:,256:512]))[N_SS:] + hh1, bf16 row-padded -------
__global__ void make_ehb_bn_kernel(const float* __restrict__ tmpBN,
                                   const float* __restrict__ stats,
                                   const float* __restrict__ g, const float* __restrict__ be,
                                   const float* __restrict__ hh1,
                                   ushort* __restrict__ out, int Rp) {
    int i = blockIdx.x * blockDim.x + threadIdx.x;
    if (i >= Rp * 256) return;
    int r = i >> 8, c = i & 255;
    float v = 0.f;
    if (r < N_HH) {
        float invM = 1.0f / (float)N_SH;
        int j = 256 + c;
        float mean = stats[j] * invM;
        float var  = fmaxf(stats[512 + j] * invM - mean * mean, 0.f);
        float x = tmpBN[(size_t)(N_SS + r) * 512 + j];
        float y = tanhf((x - mean) * rsqrtf(var + 1e-5f) * g[c] + be[c]);
        v = y + hh1[(size_t)r * 256 + c];
    }
    out[i] = f2bf(v);
}

// ---------------- driver -----------------------------------------------------
extern "C" void kernel_launch(void* const* d_in, const int* in_sizes, int n_in,
                              void* d_out, int out_size, void* d_ws, size_t ws_size,
                              hipStream_t stream) {
    const int*   eiSH = (const int*)d_in[1];
    const int*   eiSS = (const int*)d_in[3];
    const int*   eiHH = (const int*)d_in[5];
    const float* P    = (const float*)d_in[6];
    const float* kg   = (const float*)d_in[7];
    const float* emb  = (const float*)d_in[8];
    const float* w_sh1  = (const float*)d_in[9];   const float* b_sh1  = (const float*)d_in[10];
    const float* w_sh2  = (const float*)d_in[11];  const float* b_sh2  = (const float*)d_in[12];
    const float* w_mlp1 = (const float*)d_in[13];  const float* b_mlp1 = (const float*)d_in[14];
    const float* g_bn1  = (const float*)d_in[15];  const float* be_bn1 = (const float*)d_in[16];
    const float* w_sh1h = (const float*)d_in[17];  const float* b_sh1h = (const float*)d_in[18];
    const float* w_sh2h = (const float*)d_in[19];  const float* b_sh2h = (const float*)d_in[20];
    const float* w_mlp1h= (const float*)d_in[21];  const float* b_mlp1h= (const float*)d_in[22];
    const float* g_bn1h = (const float*)d_in[23];  const float* be_bn1h= (const float*)d_in[24];
    const float* w_ss   = (const float*)d_in[25];  const float* b_ss   = (const float*)d_in[26];
    const float* w_hh   = (const float*)d_in[27];  const float* b_hh   = (const float*)d_in[28];
    const float* w_mlp  = (const float*)d_in[29];  const float* b_mlp  = (const float*)d_in[30];
    const float* g_si   = (const float*)d_in[31];  const float* be_si  = (const float*)d_in[32];
    float* out = (float*)d_out;

    const int E_SH = in_sizes[1] / 2;
    const int E_SS = in_sizes[3] / 2;
    const int E_HH = in_sizes[5] / 2;
    const int B    = in_sizes[6] / N_SS;      // 20000
    const int Mp   = ((B + 127) / 128) * 128; // 20096
    const int KP1  = 416;
    const int NP3  = 896;
    const int KSH  = 1216;
    const int KHH  = 832;
    const int HS_SH = (N_SH + 3) / 4;
    const int HS_SS = (N_SS + 3) / 4;
    const int HS_HH = (N_HH + 3) / 4;

    float* w = (float*)d_ws;
    size_t off = 0;
    auto alloc = [&](size_t n) { float* p = w + off; off += (n + 3) & ~(size_t)3; return p; };

    float* cntInv   = alloc(N_SH);
    float* statsCat = alloc(1024);
    float* statsC2  = alloc(512);
    ushort* HT      = (ushort*)alloc((size_t)128 * KSH / 2);
    ushort* HSST    = (ushort*)alloc((size_t)256 * KP1 / 2);
    ushort* HHHT    = (ushort*)alloc((size_t)256 * KHH / 2);
    ushort* eswT    = (ushort*)alloc((size_t)256 * KP1 / 2);
    float* W1cat   = alloc(64 * 128);
    float* b1cat   = alloc(128);
    float* W2bd    = alloc(128 * 128);
    float* b2cat   = alloc(128);
    float* WMbd    = alloc(128 * 512);
    float* bMcat   = alloc(512);
    ushort* adjb   = (ushort*)alloc((size_t)1280 * KSH / 2);
    ushort* adjSSb = (ushort*)alloc((size_t)512 * KP1 / 2);
    ushort* adjHHb = (ushort*)alloc((size_t)896 * KHH / 2);
    float* x2cat   = alloc((size_t)N_SH * 128);
    float* x9a2    = alloc((size_t)N_SH * 128);
    float* tmpBN   = alloc((size_t)N_SH * 512);
    float* ss1     = alloc((size_t)N_SS * 256);
    float* hh1     = alloc((size_t)N_HH * 256);
    float* xhh0    = alloc((size_t)N_HH * 91);
    ushort* eh_b   = (ushort*)alloc((size_t)NP3 * 256 / 2);
    float* regionA = alloc((size_t)Mp * 256);
    uint32_t* uSH  = (uint32_t*)regionA;
    uint32_t* uSS  = uSH + (size_t)N_SH * HS_SH;
    uint32_t* uHH  = uSS + (size_t)N_SS * HS_SS;
    size_t packed_words = (size_t)N_SH * HS_SH + (size_t)N_SS * HS_SS + (size_t)N_HH * HS_HH;
    float*  bufM   = regionA;
    float* regionB = alloc((size_t)Mp * 256);
    float*  partials = regionB;
    float*  pSS = regionB;
    float*  pHH = regionB + (size_t)4 * N_SS * 256;
    (void)ws_size; (void)n_in; (void)out_size;

    const int nZeroF = 1536;
    const int nZeroH = 128 * KSH + 256 * KP1 + 256 * KHH + 256 * KP1;

    auto gemmT = [&](const float* Am, const float* A2m, int lda1, int lda2,
                     const float* Bm, const float* bias,
                     ushort* oT, int ldt, int M, int N, int K,
                     const float* bnS, const float* bnG, const float* bnB, int bnM) {
        dim3 g((N + BN - 1) / BN, (M + BM - 1) / BM);
        gemm_kernel<<<g, 256, 0, stream>>>(Am, A2m, lda1, lda2, Bm, bias,
                                           nullptr, oT, ldt, M, N, K, nullptr, 0,
                                           bnS, bnG, bnB, bnM);
    };
    auto gemmF = [&](const float* Am, const float* Bm, const float* bias,
                     float* C, int M, int N, int K, float* st, int sstride) {
        dim3 g((N + BN - 1) / BN, (M + BM - 1) / BM);
        gemm_kernel<<<g, 256, 0, stream>>>(Am, nullptr, K, 0, Bm, bias,
                                           C, nullptr, 0, M, N, K, st, sstride,
                                           nullptr, nullptr, nullptr, 0);
    };
    auto splitk = [&](const ushort* Am, const ushort* Bm, int M, int Mtiles, int K, int lda,
                      int Ntot, int S, const float* rs, const float* embA, const float* prev,
                      float* outp) {
        dim3 g(Ntot / 128, Mtiles, S);
        mfma_splitk_kernel<<<g, 256, 0, stream>>>(Am, Bm, M, K, lda, 128, Ntot, partials);
        reduce_tanh_kernel<<<(M * Ntot + 255) / 256, 256, 0, stream>>>(
            partials, S, M, Ntot, rs, embA, prev, outp);
    };

    // ---- memset: packed tables only (rest zeroed in mega_prep) ----
    hipMemsetAsync(uSH, 0, packed_words * sizeof(uint32_t), stream);

    // ---- adjacency build (atomic floor: ~E x 32B memory-side traffic) ----
    {
        int Etot = E_SH + E_SS + E_HH;
        build_adj3_kernel<<<(Etot + 255) / 256, 256, 0, stream>>>(
            eiSH, E_SH, HS_SH, uSH, eiSS, E_SS, HS_SS, uSS, eiHH, E_HH, HS_HH, uHH);
    }
    // ---- mega-prep ----
    {
        int n1 = 1280 * KSH, n2 = 512 * KP1, n3 = 896 * KHH;
        long long tot = (long long)n1 + n2 + n3 + N_SH * 64 + 90880 + N_HH * 91
                        + nZeroF + nZeroH;
        mega_prep_kernel<<<(unsigned)((tot + 255) / 256), 256, 0, stream>>>(
            uSH, HS_SH, adjb, n1, KSH, uSS, HS_SS, adjSSb, n2, KP1,
            uHH, HS_HH, adjHHb, n3, KHH, cntInv,
            w_sh1, w_sh1h, b_sh1, b_sh1h, w_sh2, w_sh2h, b_sh2, b_sh2h,
            w_mlp1, w_mlp1h, b_mlp1, b_mlp1h,
            W1cat, b1cat, W2bd, b2cat, WMbd, bMcat,
            emb, kg, xhh0,
            statsCat, nZeroF, HT, nZeroH);
    }

    // ---- SS + HH linear layers (merged) ----
    {
        dim3 g(4, 13, 2);
        gemm_side_kernel<<<g, 256, 0, stream>>>(emb, w_ss, b_ss, HSST,
                                                xhh0, w_hh, b_hh, HHHT, KP1, KHH);
    }
    // ---- SS + HH adjacency SpMM (merged) ----
    {
        dim3 g(2, 7, 11);
        mfma_splitk_side_kernel<<<g, 256, 0, stream>>>(
            adjSSb, HSST, KP1, pSS, adjHHb, HHHT, KHH, pHH);
        int totE = N_SS * 256 + N_HH * 256;
        reduce_side_kernel<<<(totE + 255) / 256, 256, 0, stream>>>(pSS, ss1, pHH, hh1);
    }

    // ---- SH layers (fused branches) ----
    gemmT(emb, nullptr, 64, 0, W1cat, b1cat, HT, KSH, N_SH, 128, 64,
          nullptr, nullptr, nullptr, 0);
    splitk(adjb, HT, N_SH, 10, KSH, KSH, 128, 10, cntInv, nullptr, nullptr, x2cat);
    gemmT(x2cat, nullptr, 128, 0, W2bd, b2cat, HT, KSH, N_SH, 128, 128,
          nullptr, nullptr, nullptr, 0);
    splitk(adjb, HT, N_SH, 10, KSH, KSH, 128, 10, cntInv, emb, x2cat, x9a2);
    gemmF(x9a2, WMbd, bMcat, tmpBN, N_SH, 512, 128, statsCat, 512);

    // ---- eh operand (BN+tanh fused) ----
    make_ehb_bn_kernel<<<(NP3 * 256 + 255) / 256, 256, 0, stream>>>(
        tmpBN, statsCat, g_bn1h, be_bn1h, hh1, eh_b, NP3);

    // ---- prescription path ----
    gemmT(tmpBN, ss1, 512, 256, w_mlp, nullptr, eswT, KP1, N_SS, 256, 256,
          statsCat, g_bn1, be_bn1, N_SH);
    {
        dim3 g(2, (B + 127) / 128);
        mfma_c1_kernel<<<g, 256, 0, stream>>>(P, eswT, B, b_mlp, bufM, statsC2);
    }
    {
        dim3 g(NP3 / 128, (B + 127) / 128);
        mfma_c3_kernel<<<g, 256, 0, stream>>>(bufM, eh_b, B, N_HH, statsC2, g_si, be_si, out, N_HH);
    }
}